// Round 2
// baseline (92.507 us; speedup 1.0000x reference)
//
#include <hip/hip_runtime.h>
#include <math.h>

// MAM dense: C[i,j] = max_k(A[i,k]*W[j,k]) + min_k(A[i,k]*W[j,k]) + bias[j]
// A = x flattened [M=2048, K=768]; W = weight [N=768, K=768]; out [M, N] f32.
// Pure VALU kernel. Key idea this round: k-pair-interleaved LDS tiles so the
// inner loop is 1 v_pk_mul_f32 + 1 v_max3_f32 + 1 v_min3_f32 per 2 k's per output.

#define M_DIM 2048
#define N_DIM 768
#define K_DIM 768

#define BM 64
#define BN 32
#define BK 32
// 256 threads: 16 (m-dir) x 16 (n-dir), TM=4 x TN=2 outputs each.
// grid = (768/32) x (2048/64) = 24 x 32 = 768 blocks = exactly 3/CU.

typedef __attribute__((ext_vector_type(2))) float f32x2;
typedef __attribute__((ext_vector_type(4))) float f32x4;

// LDS word strides (floats). Rows are k-PAIRS (BK/2 = 16 of them).
// As row: BM float2 = 128 words, +4 pad -> 132 (mult of 4 keeps b128 reads 16B-aligned)
#define SA 132
// Bs row: BN float2 = 64 words, +4 pad -> 68
#define SB 68

__global__ __launch_bounds__(256, 3) void mam_kernel(
    const float* __restrict__ A, const float* __restrict__ W,
    const float* __restrict__ bias, float* __restrict__ out)
{
    __shared__ float As[(BK / 2) * SA];  // As[kk2*SA + 2*m] = {A[k0][m], A[k1][m]}
    __shared__ float Bs[(BK / 2) * SB];  // Bs[kk2*SB + 2*n] = {B[k0][n], B[k1][n]}

    const int tid = threadIdx.x;
    const int m0 = blockIdx.y * BM;
    const int n0 = blockIdx.x * BN;
    const int mt = tid >> 4;   // 0..15, m-dir thread index (4 rows each)
    const int nt = tid & 15;   // 0..15, n-dir thread index (2 cols each)

    float amax[4][2], amin[4][2];
#pragma unroll
    for (int i = 0; i < 4; ++i)
#pragma unroll
        for (int j = 0; j < 2; ++j) {
            amax[i][j] = -INFINITY;
            amin[i][j] =  INFINITY;
        }

    // staging assignments
    const int ar  = tid >> 2;          // 0..63  : A row (m) within tile
    const int ac  = (tid & 3) * 8;     // 0,8,16,24 : A k-offset (8 floats)
    const int ac2 = (tid & 3) * 4;     // k-pair index of ac
    const int br  = tid >> 3;          // 0..31  : W row (j=n) within tile
    const int bc  = (tid & 7) * 4;     // 0..28  : W k-offset (4 floats)
    const int bc2 = (tid & 7) * 2;     // k-pair index of bc

    const float* Ap = A + (size_t)(m0 + ar) * K_DIM + ac;
    const float* Wp = W + (size_t)(n0 + br) * K_DIM + bc;

    for (int k0 = 0; k0 < K_DIM; k0 += BK) {
        const float4 av0 = *(const float4*)(Ap + k0);
        const float4 av1 = *(const float4*)(Ap + k0 + 4);
        const float4 bv  = *(const float4*)(Wp + k0);

        __syncthreads();   // previous tile's reads complete before overwrite

        // k-pair-interleaved stores (all float2 = b64, <=2-way banks)
        *(float2*)&As[(ac2 + 0) * SA + 2 * ar] = make_float2(av0.x, av0.y);
        *(float2*)&As[(ac2 + 1) * SA + 2 * ar] = make_float2(av0.z, av0.w);
        *(float2*)&As[(ac2 + 2) * SA + 2 * ar] = make_float2(av1.x, av1.y);
        *(float2*)&As[(ac2 + 3) * SA + 2 * ar] = make_float2(av1.z, av1.w);

        *(float2*)&Bs[(bc2 + 0) * SB + 2 * br] = make_float2(bv.x, bv.y);
        *(float2*)&Bs[(bc2 + 1) * SB + 2 * br] = make_float2(bv.z, bv.w);

        __syncthreads();

#pragma unroll
        for (int kk2 = 0; kk2 < BK / 2; ++kk2) {
            // {A[k0][m0],A[k1][m0],A[k0][m1],A[k1][m1]} etc — pairs pre-packed
            const f32x4 a01 = *(const f32x4*)&As[kk2 * SA + (mt * 4 + 0) * 2];
            const f32x4 a23 = *(const f32x4*)&As[kk2 * SA + (mt * 4 + 2) * 2];
            const f32x4 b01 = *(const f32x4*)&Bs[kk2 * SB + (nt * 2) * 2];

            const f32x2 pa[4] = {a01.xy, a01.zw, a23.xy, a23.zw};
            const f32x2 pb[2] = {b01.xy, b01.zw};

#pragma unroll
            for (int i = 0; i < 4; ++i)
#pragma unroll
                for (int j = 0; j < 2; ++j) {
                    const f32x2 p = pa[i] * pb[j];  // v_pk_mul_f32: 2 products, 1 instr
                    amax[i][j] = fmaxf(amax[i][j], fmaxf(p.x, p.y));  // -> v_max3_f32
                    amin[i][j] = fminf(amin[i][j], fminf(p.x, p.y));  // -> v_min3_f32
                }
        }
    }

    const float bv0 = bias[n0 + nt * 2 + 0];
    const float bv1 = bias[n0 + nt * 2 + 1];
#pragma unroll
    for (int i = 0; i < 4; ++i) {
        float2 o;
        o.x = amax[i][0] + amin[i][0] + bv0;
        o.y = amax[i][1] + amin[i][1] + bv1;
        *(float2*)&out[(size_t)(m0 + mt * 4 + i) * N_DIM + n0 + nt * 2] = o;
    }
}

extern "C" void kernel_launch(void* const* d_in, const int* in_sizes, int n_in,
                              void* d_out, int out_size, void* d_ws, size_t ws_size,
                              hipStream_t stream) {
    const float* x    = (const float*)d_in[0];   // [2,1024,768] -> [2048,768]
    const float* w    = (const float*)d_in[1];   // [768,768] row-major [N][K]
    const float* bias = (const float*)d_in[2];   // [768]
    float* out = (float*)d_out;                  // [2048,768]

    dim3 grid(N_DIM / BN, M_DIM / BM);           // (24, 32) = 768 blocks
    mam_kernel<<<grid, 256, 0, stream>>>(x, w, bias, out);
}